// Round 3
// baseline (454.861 us; speedup 1.0000x reference)
//
#include <hip/hip_runtime.h>

#define SLEN 2048
#define DIM  64
#define NH   8
#define TQ   16
#define NEG_INF -1e9f

typedef __attribute__((ext_vector_type(8))) short short8;
typedef __attribute__((ext_vector_type(4))) float f32x4;
typedef unsigned short ushort;

__device__ inline ushort f2bf(float x) {
    unsigned u = __float_as_uint(x);
    u += 0x7fffu + ((u >> 16) & 1u);          // RNE (inputs finite)
    return (ushort)(u >> 16);
}
__device__ inline float bf2f(ushort b) {
    return __uint_as_float(((unsigned)b) << 16);
}

// ---- precompute 1: K -> bf16 hi/lo (vectorized, 4 elem/thread) ----
__global__ __launch_bounds__(256)
void convk_kernel(const float* __restrict__ k,
                  ushort* __restrict__ khi, ushort* __restrict__ klo)
{
    int i4 = blockIdx.x * 256 + threadIdx.x;      // float4 index
    float4 x = ((const float4*)k)[i4];
    ushort h0 = f2bf(x.x), h1 = f2bf(x.y), h2 = f2bf(x.z), h3 = f2bf(x.w);
    ushort4 hi = {h0, h1, h2, h3};
    ushort4 lo = {f2bf(x.x - bf2f(h0)), f2bf(x.y - bf2f(h1)),
                  f2bf(x.z - bf2f(h2)), f2bf(x.w - bf2f(h3))};
    ((ushort4*)khi)[i4] = hi;
    ((ushort4*)klo)[i4] = lo;
}

// ---- precompute 2: V -> V^T bf16 via LDS tile transpose ----
__global__ __launch_bounds__(256)
void convv_kernel(const float* __restrict__ v, ushort* __restrict__ vt)
{
    __shared__ ushort sT[64][70];     // [d][s], padded
    const int h  = blockIdx.x >> 5;
    const int st = blockIdx.x & 31;   // s-tile of 64
    const int t  = threadIdx.x;
    {
        const int r0 = t >> 4;            // s row (stride 16)
        const int c  = (t & 15) * 4;      // d col
        #pragma unroll
        for (int rr = r0; rr < 64; rr += 16) {
            float4 x = *(const float4*)(v + ((size_t)(h * SLEN + st * 64 + rr)) * DIM + c);
            sT[c + 0][rr] = f2bf(x.x);
            sT[c + 1][rr] = f2bf(x.y);
            sT[c + 2][rr] = f2bf(x.z);
            sT[c + 3][rr] = f2bf(x.w);
        }
    }
    __syncthreads();
    {
        const int d  = t >> 2;
        const int s0 = (t & 3) * 16;
        short8 a = *(const short8*)(&sT[d][s0]);
        short8 b = *(const short8*)(&sT[d][s0 + 8]);
        ushort* dst = vt + ((size_t)(h * DIM + d)) * SLEN + st * 64 + s0;
        *(short8*)(dst)     = a;
        *(short8*)(dst + 8) = b;
    }
}

// ---- main: one block = (head, 16 q-rows); 8 waves; MFMA everywhere ----
// launch_bounds (512,4): cap total regs at 128/lane -> 2 blocks/CU.
__global__ __launch_bounds__(512, 4)
void attn_mfma_kernel(const float* __restrict__ q,
                      const ushort* __restrict__ khi,
                      const ushort* __restrict__ klo,
                      const ushort* __restrict__ vt,
                      const float* __restrict__ sph,
                      const int*   __restrict__ mask,
                      float* __restrict__ out,     // [H,S,D]
                      float* __restrict__ p_out)   // [H,S,S]
{
    __shared__ ushort sP[TQ][SLEN + 8];   // p tile bf16, 65792 B
    __shared__ ushort sQhi[TQ][72];       // 2304 B
    __shared__ ushort sQlo[TQ][72];       // 2304 B
    __shared__ float sMax[TQ][8];         // 512 B
    __shared__ float sSum[TQ][8];         // 512 B
    __shared__ float sC[4][TQ][16];       // 4096 B   (total ~75.5 KB, 2 blocks/CU)

    const int tid  = threadIdx.x;
    const int wave = tid >> 6;
    const int lane = tid & 63;
    const int quad = lane >> 4;
    const int l16  = lane & 15;
    // XCD-chunked bijective swizzle: 1024 wgs = 8 XCDs x 128. Each XCD then
    // works exactly one head -> khi/klo/vt working set fits 4 MB L2.
    const int bx0  = blockIdx.x;
    const int bx   = ((bx0 & 7) << 7) | (bx0 >> 3);
    const int h    = bx >> 7;
    const int qr0  = (bx & 127) * TQ;

    // ---- Q tile load + hi/lo split into LDS ----
    {
        int e = tid * 2;
        int r = e >> 6, d = e & 63;
        float2 qv = *(const float2*)(q + ((size_t)(h * SLEN + qr0 + r)) * DIM + d);
        ushort h0 = f2bf(qv.x), h1 = f2bf(qv.y);
        sQhi[r][d]     = h0;
        sQhi[r][d + 1] = h1;
        sQlo[r][d]     = f2bf(qv.x - bf2f(h0));
        sQlo[r][d + 1] = f2bf(qv.y - bf2f(h1));
    }
    __syncthreads();

    // A-fragments for Q (persistent): A[m=l16][k=quad*8+j]
    short8 ah0 = *(const short8*)(&sQhi[l16][quad * 8]);
    short8 ah1 = *(const short8*)(&sQhi[l16][32 + quad * 8]);
    short8 al0 = *(const short8*)(&sQlo[l16][quad * 8]);
    short8 al1 = *(const short8*)(&sQlo[l16][32 + quad * 8]);

    const int n0 = wave * 256;   // this wave's 256 k-columns

    f32x4 c[16];
    #pragma unroll
    for (int t = 0; t < 16; ++t) c[t] = (f32x4){0.f, 0.f, 0.f, 0.f};

    // ---- QK^T: 16 n-tiles x (2 k-steps x 3 hi/lo terms) ----
    #pragma unroll
    for (int t = 0; t < 16; ++t) {
        const size_t rowb = ((size_t)(h * SLEN + n0 + t * 16 + l16)) * DIM + quad * 8;
        short8 bh0 = *(const short8*)(khi + rowb);
        short8 bh1 = *(const short8*)(khi + rowb + 32);
        short8 bl0 = *(const short8*)(klo + rowb);
        short8 bl1 = *(const short8*)(klo + rowb + 32);
        c[t] = __builtin_amdgcn_mfma_f32_16x16x32_bf16(ah0, bh0, c[t], 0, 0, 0);
        c[t] = __builtin_amdgcn_mfma_f32_16x16x32_bf16(ah1, bh1, c[t], 0, 0, 0);
        c[t] = __builtin_amdgcn_mfma_f32_16x16x32_bf16(ah0, bl0, c[t], 0, 0, 0);
        c[t] = __builtin_amdgcn_mfma_f32_16x16x32_bf16(ah1, bl1, c[t], 0, 0, 0);
        c[t] = __builtin_amdgcn_mfma_f32_16x16x32_bf16(al0, bh0, c[t], 0, 0, 0);
        c[t] = __builtin_amdgcn_mfma_f32_16x16x32_bf16(al1, bh1, c[t], 0, 0, 0);
    }

    // ---- sph * mask + per-row max: counted-vmcnt ring pipeline ----
    // Ring of 5 one-tile chunks (8 loads each). Consume tile t waits with 4
    // newer tiles (32 loads) still in flight -> stream never drains to 0
    // (round-1's sched_barrier chunks forced a vmcnt(0) sawtooth 4x).
    // C layout: row = quad*4+j, col = n0 + t*16 + l16.
    unsigned ro[4];
    #pragma unroll
    for (int j = 0; j < 4; ++j)
        ro[j] = (unsigned)((h * SLEN + qr0 + quad * 4 + j) * SLEN + n0 + l16);

    float sv[5][4];
    int   mv[5][4];
    float rmax[4] = {-3.4e38f, -3.4e38f, -3.4e38f, -3.4e38f};

    #pragma unroll
    for (int t = 0; t < 5; ++t) {            // prologue: 40 loads in flight
        #pragma unroll
        for (int j = 0; j < 4; ++j) {
            sv[t][j] = sph [ro[j] + t * 16];
            mv[t][j] = mask[ro[j] + t * 16];
        }
    }
    #pragma unroll
    for (int t = 0; t < 16; ++t) {
        const int slot = t % 5;
        #pragma unroll
        for (int j = 0; j < 4; ++j) {
            float s = c[t][j] * 0.125f * sv[slot][j];
            s = (mv[slot][j] == 0) ? NEG_INF : s;
            c[t][j] = s;
            rmax[j] = fmaxf(rmax[j], s);
        }
        if (t + 5 < 16) {                    // refill freed slot
            #pragma unroll
            for (int j = 0; j < 4; ++j) {
                sv[slot][j] = sph [ro[j] + (t + 5) * 16];
                mv[slot][j] = mask[ro[j] + (t + 5) * 16];
            }
        }
        // pin issue-early / consume-late ordering; keeps ring lifetimes tight
        __builtin_amdgcn_sched_barrier(0);
    }

    #pragma unroll
    for (int off = 1; off <= 8; off <<= 1) {
        #pragma unroll
        for (int j = 0; j < 4; ++j)
            rmax[j] = fmaxf(rmax[j], __shfl_xor(rmax[j], off));
    }
    if (l16 == 0) {
        #pragma unroll
        for (int j = 0; j < 4; ++j) sMax[quad * 4 + j][wave] = rmax[j];
    }
    __syncthreads();

    float M[4];
    #pragma unroll
    for (int j = 0; j < 4; ++j) {
        float m = sMax[quad * 4 + j][0];
        #pragma unroll
        for (int w = 1; w < 8; ++w) m = fmaxf(m, sMax[quad * 4 + j][w]);
        M[j] = m;
    }

    float rsum[4] = {0.f, 0.f, 0.f, 0.f};
    #pragma unroll
    for (int t = 0; t < 16; ++t) {
        #pragma unroll
        for (int j = 0; j < 4; ++j) {
            float e = __expf(c[t][j] - M[j]);
            c[t][j] = e;
            rsum[j] += e;
        }
    }
    #pragma unroll
    for (int off = 1; off <= 8; off <<= 1) {
        #pragma unroll
        for (int j = 0; j < 4; ++j)
            rsum[j] += __shfl_xor(rsum[j], off);
    }
    if (l16 == 0) {
        #pragma unroll
        for (int j = 0; j < 4; ++j) sSum[quad * 4 + j][wave] = rsum[j];
    }
    __syncthreads();

    float inv[4];
    #pragma unroll
    for (int j = 0; j < 4; ++j) {
        float s = 0.f;
        #pragma unroll
        for (int w = 0; w < 8; ++w) s += sSum[quad * 4 + j][w];
        inv[j] = 1.0f / s;
    }

    // ---- normalize; write p fp32 to global (plain stores -> L2 line
    // combining), bf16 to LDS ----
    #pragma unroll
    for (int t = 0; t < 16; ++t) {
        #pragma unroll
        for (int j = 0; j < 4; ++j) {
            const int row = quad * 4 + j;
            const int col = n0 + t * 16 + l16;
            float p = c[t][j] * inv[j];
            p_out[ro[j] + t * 16] = p;
            sP[row][col] = f2bf(p);
        }
    }
    __syncthreads();

    // ---- PV: wave -> (ntile = d-block, khalf); 32 k-steps of 32 ----
    const int ntile = wave & 3;
    const int khalf = wave >> 2;
    f32x4 o = (f32x4){0.f, 0.f, 0.f, 0.f};
    const ushort* vb = vt + ((size_t)(h * DIM + ntile * 16 + l16)) * SLEN
                          + khalf * 1024 + quad * 8;
    #pragma unroll 8
    for (int s = 0; s < 32; ++s) {
        short8 a = *(const short8*)(&sP[l16][khalf * 1024 + s * 32 + quad * 8]);
        short8 b = *(const short8*)(vb + s * 32);
        o = __builtin_amdgcn_mfma_f32_16x16x32_bf16(a, b, o, 0, 0, 0);
    }
    if (wave >= 4) {
        #pragma unroll
        for (int j = 0; j < 4; ++j) sC[ntile][quad * 4 + j][l16] = o[j];
    }
    __syncthreads();
    if (wave < 4) {
        #pragma unroll
        for (int j = 0; j < 4; ++j) {
            float r = o[j] + sC[ntile][quad * 4 + j][l16];
            out[((size_t)(h * SLEN) + qr0 + quad * 4 + j) * DIM + ntile * 16 + l16] = r;
        }
    }
}

extern "C" void kernel_launch(void* const* d_in, const int* in_sizes, int n_in,
                              void* d_out, int out_size, void* d_ws, size_t ws_size,
                              hipStream_t stream) {
    const float* q    = (const float*)d_in[0];
    const float* k    = (const float*)d_in[1];
    const float* v    = (const float*)d_in[2];
    const float* sph  = (const float*)d_in[3];
    const int*   mask = (const int*)d_in[4];
    float* out   = (float*)d_out;                       // [8,2048,64]
    float* p_out = out + (size_t)NH * SLEN * DIM;       // [8,2048,2048]

    const size_t nkv = (size_t)NH * SLEN * DIM;         // 1,048,576
    ushort* khi = (ushort*)d_ws;                        // 2 MB
    ushort* klo = khi + nkv;                            // 2 MB
    ushort* vt  = klo + nkv;                            // 2 MB

    hipLaunchKernelGGL(convk_kernel, dim3(nkv / 4 / 256), dim3(256), 0, stream,
                       k, khi, klo);
    hipLaunchKernelGGL(convv_kernel, dim3(NH * (SLEN / 64)), dim3(256), 0, stream,
                       v, vt);
    hipLaunchKernelGGL(attn_mfma_kernel, dim3(NH * (SLEN / TQ)), dim3(512), 0, stream,
                       q, khi, klo, vt, sph, mask, out, p_out);
}

// Round 4
// 397.495 us; speedup vs baseline: 1.1443x; 1.1443x over previous
//
#include <hip/hip_runtime.h>

#define SLEN 2048
#define DIM  64
#define NH   8
#define TQ   16
#define NEG_INF -1e9f

typedef __attribute__((ext_vector_type(8))) short short8;
typedef __attribute__((ext_vector_type(4))) float f32x4;
typedef unsigned short ushort;

__device__ inline ushort f2bf(float x) {
    unsigned u = __float_as_uint(x);
    u += 0x7fffu + ((u >> 16) & 1u);          // RNE (inputs finite)
    return (ushort)(u >> 16);
}
__device__ inline float bf2f(ushort b) {
    return __uint_as_float(((unsigned)b) << 16);
}

// ---- precompute 1: K -> bf16 hi/lo (vectorized, 4 elem/thread) ----
__global__ __launch_bounds__(256)
void convk_kernel(const float* __restrict__ k,
                  ushort* __restrict__ khi, ushort* __restrict__ klo)
{
    int i4 = blockIdx.x * 256 + threadIdx.x;      // float4 index
    float4 x = ((const float4*)k)[i4];
    ushort h0 = f2bf(x.x), h1 = f2bf(x.y), h2 = f2bf(x.z), h3 = f2bf(x.w);
    ushort4 hi = {h0, h1, h2, h3};
    ushort4 lo = {f2bf(x.x - bf2f(h0)), f2bf(x.y - bf2f(h1)),
                  f2bf(x.z - bf2f(h2)), f2bf(x.w - bf2f(h3))};
    ((ushort4*)khi)[i4] = hi;
    ((ushort4*)klo)[i4] = lo;
}

// ---- precompute 2: V -> V^T bf16 via LDS tile transpose ----
__global__ __launch_bounds__(256)
void convv_kernel(const float* __restrict__ v, ushort* __restrict__ vt)
{
    __shared__ ushort sT[64][70];     // [d][s], padded
    const int h  = blockIdx.x >> 5;
    const int st = blockIdx.x & 31;   // s-tile of 64
    const int t  = threadIdx.x;
    {
        const int r0 = t >> 4;            // s row (stride 16)
        const int c  = (t & 15) * 4;      // d col
        #pragma unroll
        for (int rr = r0; rr < 64; rr += 16) {
            float4 x = *(const float4*)(v + ((size_t)(h * SLEN + st * 64 + rr)) * DIM + c);
            sT[c + 0][rr] = f2bf(x.x);
            sT[c + 1][rr] = f2bf(x.y);
            sT[c + 2][rr] = f2bf(x.z);
            sT[c + 3][rr] = f2bf(x.w);
        }
    }
    __syncthreads();
    {
        const int d  = t >> 2;
        const int s0 = (t & 3) * 16;
        short8 a = *(const short8*)(&sT[d][s0]);
        short8 b = *(const short8*)(&sT[d][s0 + 8]);
        ushort* dst = vt + ((size_t)(h * DIM + d)) * SLEN + st * 64 + s0;
        *(short8*)(dst)     = a;
        *(short8*)(dst + 8) = b;
    }
}

// ---- main: one block = (head, 16 q-rows); 8 waves; MFMA everywhere ----
// (512,2): 1 block/CU, ~256-reg budget. Trades residency (round 0->1 showed
// it bought only 9% -- blocks convoy) for deterministic in-block overlap of
// the sph/mask HBM stream under the QK^T MFMA phase via an 8-tile reg ring.
__global__ __launch_bounds__(512, 2)
void attn_mfma_kernel(const float* __restrict__ q,
                      const ushort* __restrict__ khi,
                      const ushort* __restrict__ klo,
                      const ushort* __restrict__ vt,
                      const float* __restrict__ sph,
                      const int*   __restrict__ mask,
                      float* __restrict__ out,     // [H,S,D]
                      float* __restrict__ p_out)   // [H,S,S]
{
    __shared__ ushort sP[TQ][SLEN + 8];   // p tile bf16, 65792 B
    __shared__ ushort sQhi[TQ][72];       // 2304 B
    __shared__ ushort sQlo[TQ][72];       // 2304 B
    __shared__ float sMax[TQ][8];         // 512 B
    __shared__ float sSum[TQ][8];         // 512 B
    __shared__ float sC[4][TQ][16];       // 4096 B   (total ~75.5 KB)

    const int tid  = threadIdx.x;
    const int wave = tid >> 6;
    const int lane = tid & 63;
    const int quad = lane >> 4;
    const int l16  = lane & 15;
    // XCD-chunked bijective swizzle: 1024 wgs = 8 XCDs x 128 -> each XCD
    // works exactly one head; khi/klo/vt working set (768 KB) fits 4 MB L2.
    const int bx0  = blockIdx.x;
    const int bx   = ((bx0 & 7) << 7) | (bx0 >> 3);
    const int h    = bx >> 7;
    const int qr0  = (bx & 127) * TQ;

    // ---- Q tile load + hi/lo split into LDS ----
    {
        int e = tid * 2;
        int r = e >> 6, d = e & 63;
        float2 qv = *(const float2*)(q + ((size_t)(h * SLEN + qr0 + r)) * DIM + d);
        ushort h0 = f2bf(qv.x), h1 = f2bf(qv.y);
        sQhi[r][d]     = h0;
        sQhi[r][d + 1] = h1;
        sQlo[r][d]     = f2bf(qv.x - bf2f(h0));
        sQlo[r][d + 1] = f2bf(qv.y - bf2f(h1));
    }
    __syncthreads();   // NOTE: drains vmcnt(0) -> sph/mask ring must start AFTER this

    // A-fragments for Q (persistent): A[m=l16][k=quad*8+j]
    short8 ah0 = *(const short8*)(&sQhi[l16][quad * 8]);
    short8 ah1 = *(const short8*)(&sQhi[l16][32 + quad * 8]);
    short8 al0 = *(const short8*)(&sQlo[l16][quad * 8]);
    short8 al1 = *(const short8*)(&sQlo[l16][32 + quad * 8]);

    const int n0 = wave * 256;   // this wave's 256 k-columns

    // C layout: row = quad*4+j, col = n0 + t*16 + l16 (32-bit elem offsets)
    unsigned ro[4];
    #pragma unroll
    for (int j = 0; j < 4; ++j)
        ro[j] = (unsigned)((h * SLEN + qr0 + quad * 4 + j) * SLEN + n0 + l16);

    // ---- 8-tile sph/mask ring: issue prologue BEFORE QK^T so the HBM
    // stream runs under the MFMA phase. nontemporal is load-bearing: plain
    // loads thrash L2 and break p_out write-combining (round-3: 296->514 MB).
    float sv[8][4];
    int   mv[8][4];
    #pragma unroll
    for (int t = 0; t < 8; ++t) {
        #pragma unroll
        for (int j = 0; j < 4; ++j) {
            sv[t][j] = __builtin_nontemporal_load(sph  + ro[j] + t * 16);
            mv[t][j] = __builtin_nontemporal_load(mask + ro[j] + t * 16);
        }
    }

    f32x4 c[16];
    #pragma unroll
    for (int t = 0; t < 16; ++t) c[t] = (f32x4){0.f, 0.f, 0.f, 0.f};

    float rmax[4] = {-3.4e38f, -3.4e38f, -3.4e38f, -3.4e38f};

    // ---- fused QK^T + bias/mask/max pipeline ----
    // iter t: {K loads + 6 MFMAs for tile t} -> {consume sph/mask tile t
    // (counted vmcnt: 7 newer tiles stay in flight)} -> {refill slot with
    // tile t+8}. Lead = 8 iters of MFMA >> ~900 cy HBM latency.
    #pragma unroll
    for (int t = 0; t < 16; ++t) {
        const size_t rowb = ((size_t)(h * SLEN + n0 + t * 16 + l16)) * DIM + quad * 8;
        short8 bh0 = *(const short8*)(khi + rowb);
        short8 bh1 = *(const short8*)(khi + rowb + 32);
        short8 bl0 = *(const short8*)(klo + rowb);
        short8 bl1 = *(const short8*)(klo + rowb + 32);
        c[t] = __builtin_amdgcn_mfma_f32_16x16x32_bf16(ah0, bh0, c[t], 0, 0, 0);
        c[t] = __builtin_amdgcn_mfma_f32_16x16x32_bf16(ah1, bh1, c[t], 0, 0, 0);
        c[t] = __builtin_amdgcn_mfma_f32_16x16x32_bf16(ah0, bl0, c[t], 0, 0, 0);
        c[t] = __builtin_amdgcn_mfma_f32_16x16x32_bf16(ah1, bl1, c[t], 0, 0, 0);
        c[t] = __builtin_amdgcn_mfma_f32_16x16x32_bf16(al0, bh0, c[t], 0, 0, 0);
        c[t] = __builtin_amdgcn_mfma_f32_16x16x32_bf16(al1, bh1, c[t], 0, 0, 0);

        const int slot = t & 7;
        #pragma unroll
        for (int j = 0; j < 4; ++j) {
            float s = c[t][j] * 0.125f * sv[slot][j];
            s = (mv[slot][j] == 0) ? NEG_INF : s;
            c[t][j] = s;
            rmax[j] = fmaxf(rmax[j], s);
        }
        if (t + 8 < 16) {
            #pragma unroll
            for (int j = 0; j < 4; ++j) {
                sv[slot][j] = __builtin_nontemporal_load(sph  + ro[j] + (t + 8) * 16);
                mv[slot][j] = __builtin_nontemporal_load(mask + ro[j] + (t + 8) * 16);
            }
        }
    }

    #pragma unroll
    for (int off = 1; off <= 8; off <<= 1) {
        #pragma unroll
        for (int j = 0; j < 4; ++j)
            rmax[j] = fmaxf(rmax[j], __shfl_xor(rmax[j], off));
    }
    if (l16 == 0) {
        #pragma unroll
        for (int j = 0; j < 4; ++j) sMax[quad * 4 + j][wave] = rmax[j];
    }
    __syncthreads();

    float M[4];
    #pragma unroll
    for (int j = 0; j < 4; ++j) {
        float m = sMax[quad * 4 + j][0];
        #pragma unroll
        for (int w = 1; w < 8; ++w) m = fmaxf(m, sMax[quad * 4 + j][w]);
        M[j] = m;
    }

    float rsum[4] = {0.f, 0.f, 0.f, 0.f};
    #pragma unroll
    for (int t = 0; t < 16; ++t) {
        #pragma unroll
        for (int j = 0; j < 4; ++j) {
            float e = __expf(c[t][j] - M[j]);
            c[t][j] = e;
            rsum[j] += e;
        }
    }
    #pragma unroll
    for (int off = 1; off <= 8; off <<= 1) {
        #pragma unroll
        for (int j = 0; j < 4; ++j)
            rsum[j] += __shfl_xor(rsum[j], off);
    }
    if (l16 == 0) {
        #pragma unroll
        for (int j = 0; j < 4; ++j) sSum[quad * 4 + j][wave] = rsum[j];
    }
    __syncthreads();

    float inv[4];
    #pragma unroll
    for (int j = 0; j < 4; ++j) {
        float s = 0.f;
        #pragma unroll
        for (int w = 0; w < 8; ++w) s += sSum[quad * 4 + j][w];
        inv[j] = 1.0f / s;
    }

    // ---- normalize; write p fp32 to global (plain stores -> L2 line
    // combining; nt here re-amplifies writes, round-0 evidence), bf16 to LDS
    #pragma unroll
    for (int t = 0; t < 16; ++t) {
        #pragma unroll
        for (int j = 0; j < 4; ++j) {
            const int row = quad * 4 + j;
            const int col = n0 + t * 16 + l16;
            float p = c[t][j] * inv[j];
            p_out[ro[j] + t * 16] = p;
            sP[row][col] = f2bf(p);
        }
    }
    __syncthreads();

    // ---- PV: wave -> (ntile = d-block, khalf); 32 k-steps of 32 ----
    const int ntile = wave & 3;
    const int khalf = wave >> 2;
    f32x4 o = (f32x4){0.f, 0.f, 0.f, 0.f};
    const ushort* vb = vt + ((size_t)(h * DIM + ntile * 16 + l16)) * SLEN
                          + khalf * 1024 + quad * 8;
    #pragma unroll 8
    for (int s = 0; s < 32; ++s) {
        short8 a = *(const short8*)(&sP[l16][khalf * 1024 + s * 32 + quad * 8]);
        short8 b = *(const short8*)(vb + s * 32);
        o = __builtin_amdgcn_mfma_f32_16x16x32_bf16(a, b, o, 0, 0, 0);
    }
    if (wave >= 4) {
        #pragma unroll
        for (int j = 0; j < 4; ++j) sC[ntile][quad * 4 + j][l16] = o[j];
    }
    __syncthreads();
    if (wave < 4) {
        #pragma unroll
        for (int j = 0; j < 4; ++j) {
            float r = o[j] + sC[ntile][quad * 4 + j][l16];
            out[((size_t)(h * SLEN) + qr0 + quad * 4 + j) * DIM + ntile * 16 + l16] = r;
        }
    }
}

extern "C" void kernel_launch(void* const* d_in, const int* in_sizes, int n_in,
                              void* d_out, int out_size, void* d_ws, size_t ws_size,
                              hipStream_t stream) {
    const float* q    = (const float*)d_in[0];
    const float* k    = (const float*)d_in[1];
    const float* v    = (const float*)d_in[2];
    const float* sph  = (const float*)d_in[3];
    const int*   mask = (const int*)d_in[4];
    float* out   = (float*)d_out;                       // [8,2048,64]
    float* p_out = out + (size_t)NH * SLEN * DIM;       // [8,2048,2048]

    const size_t nkv = (size_t)NH * SLEN * DIM;         // 1,048,576
    ushort* khi = (ushort*)d_ws;                        // 2 MB
    ushort* klo = khi + nkv;                            // 2 MB
    ushort* vt  = klo + nkv;                            // 2 MB

    hipLaunchKernelGGL(convk_kernel, dim3(nkv / 4 / 256), dim3(256), 0, stream,
                       k, khi, klo);
    hipLaunchKernelGGL(convv_kernel, dim3(NH * (SLEN / 64)), dim3(256), 0, stream,
                       v, vt);
    hipLaunchKernelGGL(attn_mfma_kernel, dim3(NH * (SLEN / TQ)), dim3(512), 0, stream,
                       q, khi, klo, vt, sph, mask, out, p_out);
}